// Round 1
// baseline (5983.025 us; speedup 1.0000x reference)
//
#include <hip/hip_runtime.h>

#define D 256
#define MT 32

// ---------------------------------------------------------------------------
// Phase 2: edge scatter. One 64-lane wave per edge; lane l handles floats
// [4l, 4l+4) of the 256-wide feature row. Native f32 atomics (unsafeAtomicAdd
// -> global_atomic_add_f32; plain atomicAdd would CAS-loop without
// -munsafe-fp-atomics).
// ---------------------------------------------------------------------------
__global__ void __launch_bounds__(256) scatter_edges(
    const float* __restrict__ feat, const int* __restrict__ src,
    const int* __restrict__ dst, const float* __restrict__ ew,
    float* __restrict__ agg, int E) {
  int gid = blockIdx.x * 256 + threadIdx.x;
  int e = gid >> 6;
  int lane = threadIdx.x & 63;
  if (e >= E) return;
  int s = src[e];
  int d = dst[e];
  float wt = ew[e];
  const float4 v = *(const float4*)(feat + (size_t)s * D + lane * 4);
  float* o = agg + (size_t)d * D + lane * 4;
  unsafeAtomicAdd(o + 0, v.x * wt);
  unsafeAtomicAdd(o + 1, v.y * wt);
  unsafeAtomicAdd(o + 2, v.z * wt);
  unsafeAtomicAdd(o + 3, v.w * wt);
}

// ---------------------------------------------------------------------------
// Phase 3: in-place projection  row <- row @ W.T + b.
// Block = 256 threads (thread t owns output column t), 32 rows per block.
// A-tile (32x256 f32 = 32KB) staged in LDS, read as wave-uniform float4
// broadcasts. W staged transposed in 16-wide K chunks: Ws[kk][n] so the
// per-lane read Ws[kk][tid] walks all 32 banks conflict-free.
// In-place is safe: each block reads its own 32 rows into LDS before any
// global write, and only writes those same rows.
// ---------------------------------------------------------------------------
__global__ void __launch_bounds__(256) proj_inplace(
    float* __restrict__ io, const float* __restrict__ W,
    const float* __restrict__ bias, int M) {
  __shared__ float As[MT][D];       // 32 KB
  __shared__ float Ws[16][D + 4];   // padded stride 260 words

  const int tid = threadIdx.x;
  const int m0 = blockIdx.x * MT;

  // Load A tile (coalesced float4).
  {
    const float4* g = (const float4*)(io + (size_t)m0 * D);
    float4* s = (float4*)As;
    for (int i = tid; i < MT * (D / 4); i += 256) {
      int row = i / (D / 4);
      if (m0 + row < M) s[i] = g[i];
    }
  }

  float acc[MT];
#pragma unroll
  for (int m = 0; m < MT; ++m) acc[m] = 0.f;

  for (int kc = 0; kc < D / 16; ++kc) {
    __syncthreads();  // A tile ready (kc==0) / Ws consumers done (kc>0)
    // Stage Ws[kk][n] = W[n][kc*16+kk], coalesced float4 global reads.
    const float4* W4 = (const float4*)W;
    for (int i = tid; i < D * 4; i += 256) {
      int n = i >> 2, c = i & 3;
      float4 v = W4[(size_t)n * (D / 4) + kc * 4 + c];
      Ws[c * 4 + 0][n] = v.x;
      Ws[c * 4 + 1][n] = v.y;
      Ws[c * 4 + 2][n] = v.z;
      Ws[c * 4 + 3][n] = v.w;
    }
    __syncthreads();
#pragma unroll
    for (int q = 0; q < 4; ++q) {
      float w0 = Ws[q * 4 + 0][tid];
      float w1 = Ws[q * 4 + 1][tid];
      float w2 = Ws[q * 4 + 2][tid];
      float w3 = Ws[q * 4 + 3][tid];
#pragma unroll
      for (int m = 0; m < MT; ++m) {
        const float4 a = *(const float4*)&As[m][kc * 16 + q * 4];
        acc[m] = fmaf(a.x, w0, acc[m]);
        acc[m] = fmaf(a.y, w1, acc[m]);
        acc[m] = fmaf(a.z, w2, acc[m]);
        acc[m] = fmaf(a.w, w3, acc[m]);
      }
    }
  }

  const float bv = bias[tid];
#pragma unroll
  for (int m = 0; m < MT; ++m) {
    if (m0 + m < M) io[(size_t)(m0 + m) * D + tid] = acc[m] + bv;
  }
}

extern "C" void kernel_launch(void* const* d_in, const int* in_sizes, int n_in,
                              void* d_out, int out_size, void* d_ws, size_t ws_size,
                              hipStream_t stream) {
  const float* feat = (const float*)d_in[0];
  const int* src = (const int*)d_in[1];
  const int* dst = (const int*)d_in[2];
  const float* ew = (const float*)d_in[3];
  const float* W = (const float*)d_in[4];
  const float* bias = (const float*)d_in[5];
  float* out = (float*)d_out;

  const int E = in_sizes[1];
  const int M = out_size / D;

  // Phase 1: zero the accumulator (d_out is poisoned 0xAA before every call).
  hipMemsetAsync(out, 0, (size_t)out_size * sizeof(float), stream);

  // Phase 2: atomic scatter, one wave per edge.
  {
    long long threads = (long long)E * 64;
    int blocks = (int)((threads + 255) / 256);
    scatter_edges<<<blocks, 256, 0, stream>>>(feat, src, dst, ew, out, E);
  }

  // Phase 3: in-place dense projection.
  {
    int blocks = (M + MT - 1) / MT;
    proj_inplace<<<blocks, 256, 0, stream>>>(out, W, bias, M);
  }
}

// Round 3
// 1379.991 us; speedup vs baseline: 4.3356x; 4.3356x over previous
//
#include <hip/hip_runtime.h>

#define D 256
#define MT 32

// ---------------------------------------------------------------------------
// CSR build step 1: per-dst in-degree histogram (counts lives in cursor buf).
// ---------------------------------------------------------------------------
__global__ void __launch_bounds__(256) hist_kernel(
    const int* __restrict__ dst, int* __restrict__ counts, int E) {
  int i = blockIdx.x * 256 + threadIdx.x;
  if (i < E) atomicAdd(&counts[dst[i]], 1);
}

// ---------------------------------------------------------------------------
// CSR build step 2: exclusive scan of counts -> offsets (and cursor copy).
// Single 1024-thread block: serial chunk sums, LDS Hillis-Steele over the
// 1024 partials, serial chunk rewrite. In-place safe (counts == cursor).
// ---------------------------------------------------------------------------
__global__ void __launch_bounds__(1024) scan_kernel(
    int* __restrict__ counts_cursor, int* __restrict__ offsets, int N) {
  __shared__ int part[1024];
  const int tid = threadIdx.x;
  const int chunk = (N + 1023) / 1024;
  const int lo = tid * chunk;
  const int hi = min(lo + chunk, N);
  int s = 0;
  for (int i = lo; i < hi; ++i) s += counts_cursor[i];
  part[tid] = s;
  __syncthreads();
  for (int off = 1; off < 1024; off <<= 1) {
    int v = (tid >= off) ? part[tid - off] : 0;
    __syncthreads();
    part[tid] += v;
    __syncthreads();
  }
  int run = (tid == 0) ? 0 : part[tid - 1];
  for (int i = lo; i < hi; ++i) {
    int c = counts_cursor[i];
    offsets[i] = run;
    counts_cursor[i] = run;  // cursor for fill_kernel
    run += c;
  }
  if (tid == 1023) offsets[N] = run;  // == E
}

// ---------------------------------------------------------------------------
// CSR build step 3: place each edge id at cursor[dst]++.
// ---------------------------------------------------------------------------
__global__ void __launch_bounds__(256) fill_kernel(
    const int* __restrict__ dst, int* __restrict__ cursor,
    int* __restrict__ csr_eid, int E) {
  int i = blockIdx.x * 256 + threadIdx.x;
  if (i >= E) return;
  int pos = atomicAdd(&cursor[dst[i]], 1);
  csr_eid[pos] = i;
}

// ---------------------------------------------------------------------------
// Step 4: gather. One 64-lane wave per node; lane l owns floats [4l,4l+4).
// Per edge: wave-uniform eid/src/w loads, coalesced 1KB float4 row read
// (features are L3-resident), FMA into 4 VGPR accums; one coalesced write.
// ---------------------------------------------------------------------------
__global__ void __launch_bounds__(256) gather_kernel(
    const float* __restrict__ feat, const int* __restrict__ offsets,
    const int* __restrict__ csr_eid, const int* __restrict__ src,
    const float* __restrict__ ew, float* __restrict__ out, int N) {
  int node = (blockIdx.x * 256 + threadIdx.x) >> 6;
  int lane = threadIdx.x & 63;
  if (node >= N) return;
  int e = offsets[node];
  const int end = offsets[node + 1];
  float4 acc = {0.f, 0.f, 0.f, 0.f};
  for (; e + 2 <= end; e += 2) {
    int i0 = csr_eid[e], i1 = csr_eid[e + 1];
    int s0 = src[i0], s1 = src[i1];
    float w0 = ew[i0], w1 = ew[i1];
    float4 v0 = *(const float4*)(feat + (size_t)s0 * D + lane * 4);
    float4 v1 = *(const float4*)(feat + (size_t)s1 * D + lane * 4);
    acc.x = fmaf(v0.x, w0, acc.x); acc.y = fmaf(v0.y, w0, acc.y);
    acc.z = fmaf(v0.z, w0, acc.z); acc.w = fmaf(v0.w, w0, acc.w);
    acc.x = fmaf(v1.x, w1, acc.x); acc.y = fmaf(v1.y, w1, acc.y);
    acc.z = fmaf(v1.z, w1, acc.z); acc.w = fmaf(v1.w, w1, acc.w);
  }
  if (e < end) {
    int i0 = csr_eid[e];
    int s0 = src[i0];
    float w0 = ew[i0];
    float4 v0 = *(const float4*)(feat + (size_t)s0 * D + lane * 4);
    acc.x = fmaf(v0.x, w0, acc.x); acc.y = fmaf(v0.y, w0, acc.y);
    acc.z = fmaf(v0.z, w0, acc.z); acc.w = fmaf(v0.w, w0, acc.w);
  }
  *(float4*)(out + (size_t)node * D + lane * 4) = acc;
}

// ---------------------------------------------------------------------------
// Fallback phase (only if ws too small): atomic scatter, one wave per edge.
// ---------------------------------------------------------------------------
__global__ void __launch_bounds__(256) scatter_edges(
    const float* __restrict__ feat, const int* __restrict__ src,
    const int* __restrict__ dst, const float* __restrict__ ew,
    float* __restrict__ agg, int E) {
  int gid = blockIdx.x * 256 + threadIdx.x;
  int e = gid >> 6;
  int lane = threadIdx.x & 63;
  if (e >= E) return;
  int s = src[e];
  int d = dst[e];
  float wt = ew[e];
  const float4 v = *(const float4*)(feat + (size_t)s * D + lane * 4);
  float* o = agg + (size_t)d * D + lane * 4;
  unsafeAtomicAdd(o + 0, v.x * wt);
  unsafeAtomicAdd(o + 1, v.y * wt);
  unsafeAtomicAdd(o + 2, v.z * wt);
  unsafeAtomicAdd(o + 3, v.w * wt);
}

// ---------------------------------------------------------------------------
// Step 5: in-place projection  row <- row @ W.T + b.
// ---------------------------------------------------------------------------
__global__ void __launch_bounds__(256) proj_inplace(
    float* __restrict__ io, const float* __restrict__ W,
    const float* __restrict__ bias, int M) {
  __shared__ float As[MT][D];       // 32 KB
  __shared__ float Ws[16][D + 4];   // padded stride

  const int tid = threadIdx.x;
  const int m0 = blockIdx.x * MT;

  {
    const float4* g = (const float4*)(io + (size_t)m0 * D);
    float4* s = (float4*)As;
    for (int i = tid; i < MT * (D / 4); i += 256) {
      int row = i / (D / 4);
      if (m0 + row < M) s[i] = g[i];
    }
  }

  float acc[MT];
#pragma unroll
  for (int m = 0; m < MT; ++m) acc[m] = 0.f;

  for (int kc = 0; kc < D / 16; ++kc) {
    __syncthreads();
    const float4* W4 = (const float4*)W;
    for (int i = tid; i < D * 4; i += 256) {
      int n = i >> 2, c = i & 3;
      float4 v = W4[(size_t)n * (D / 4) + kc * 4 + c];
      Ws[c * 4 + 0][n] = v.x;
      Ws[c * 4 + 1][n] = v.y;
      Ws[c * 4 + 2][n] = v.z;
      Ws[c * 4 + 3][n] = v.w;
    }
    __syncthreads();
#pragma unroll
    for (int q = 0; q < 4; ++q) {
      float w0 = Ws[q * 4 + 0][tid];
      float w1 = Ws[q * 4 + 1][tid];
      float w2 = Ws[q * 4 + 2][tid];
      float w3 = Ws[q * 4 + 3][tid];
#pragma unroll
      for (int m = 0; m < MT; ++m) {
        const float4 a = *(const float4*)&As[m][kc * 16 + q * 4];
        acc[m] = fmaf(a.x, w0, acc[m]);
        acc[m] = fmaf(a.y, w1, acc[m]);
        acc[m] = fmaf(a.z, w2, acc[m]);
        acc[m] = fmaf(a.w, w3, acc[m]);
      }
    }
  }

  const float bv = bias[tid];
#pragma unroll
  for (int m = 0; m < MT; ++m) {
    if (m0 + m < M) io[(size_t)(m0 + m) * D + tid] = acc[m] + bv;
  }
}

extern "C" void kernel_launch(void* const* d_in, const int* in_sizes, int n_in,
                              void* d_out, int out_size, void* d_ws, size_t ws_size,
                              hipStream_t stream) {
  const float* feat = (const float*)d_in[0];
  const int* src = (const int*)d_in[1];
  const int* dst = (const int*)d_in[2];
  const float* ew = (const float*)d_in[3];
  const float* W = (const float*)d_in[4];
  const float* bias = (const float*)d_in[5];
  float* out = (float*)d_out;

  const int E = in_sizes[1];
  const int M = out_size / D;  // == N nodes

  // Workspace layout (256B-aligned sections):
  //   offsets : int[M+1]
  //   cursor  : int[M]      (doubles as counts)
  //   csr_eid : int[E]
  size_t off_b = ((size_t)(M + 1) * 4 + 255) & ~(size_t)255;
  size_t cur_b = ((size_t)M * 4 + 255) & ~(size_t)255;
  size_t eid_b = ((size_t)E * 4 + 255) & ~(size_t)255;
  size_t need = off_b + cur_b + eid_b;

  if (ws_size >= need && d_ws != nullptr) {
    char* ws = (char*)d_ws;
    int* offsets = (int*)ws;
    int* cursor = (int*)(ws + off_b);
    int* csr_eid = (int*)(ws + off_b + cur_b);

    const int eb = (E + 255) / 256;
    hipMemsetAsync(cursor, 0, (size_t)M * 4, stream);  // ws poisoned 0xAA
    hist_kernel<<<eb, 256, 0, stream>>>(dst, cursor, E);
    scan_kernel<<<1, 1024, 0, stream>>>(cursor, offsets, M);
    fill_kernel<<<eb, 256, 0, stream>>>(dst, cursor, csr_eid, E);

    long long threads = (long long)M * 64;
    int blocks = (int)((threads + 255) / 256);
    gather_kernel<<<blocks, 256, 0, stream>>>(feat, offsets, csr_eid, src, ew,
                                              out, M);
  } else {
    // Fallback: R1 atomic-scatter path (no workspace needed).
    hipMemsetAsync(out, 0, (size_t)out_size * sizeof(float), stream);
    long long threads = (long long)E * 64;
    int blocks = (int)((threads + 255) / 256);
    scatter_edges<<<blocks, 256, 0, stream>>>(feat, src, dst, ew, out, E);
  }

  proj_inplace<<<(M + MT - 1) / MT, 256, 0, stream>>>(out, W, bias, M);
}

// Round 7
// 954.491 us; speedup vs baseline: 6.2683x; 1.4458x over previous
//
#include <hip/hip_runtime.h>
#include <hip/hip_bf16.h>

#define D 256

typedef __attribute__((ext_vector_type(8))) short bf16x8;
typedef __attribute__((ext_vector_type(4))) float f32x4;

// ---------------------------------------------------------------------------
// CSR build step 1: per-dst in-degree histogram (counts lives in cursor buf).
// ---------------------------------------------------------------------------
__global__ void __launch_bounds__(256) hist_kernel(
    const int* __restrict__ dst, int* __restrict__ counts, int E) {
  int i = blockIdx.x * 256 + threadIdx.x;
  if (i < E) atomicAdd(&counts[dst[i]], 1);
}

// ---------------------------------------------------------------------------
// CSR build step 2: exclusive scan of counts -> offsets (and cursor copy).
// ---------------------------------------------------------------------------
__global__ void __launch_bounds__(1024) scan_kernel(
    int* __restrict__ counts_cursor, int* __restrict__ offsets, int N) {
  __shared__ int part[1024];
  const int tid = threadIdx.x;
  const int chunk = (N + 1023) / 1024;
  const int lo = tid * chunk;
  const int hi = min(lo + chunk, N);
  int s = 0;
  for (int i = lo; i < hi; ++i) s += counts_cursor[i];
  part[tid] = s;
  __syncthreads();
  for (int off = 1; off < 1024; off <<= 1) {
    int v = (tid >= off) ? part[tid - off] : 0;
    __syncthreads();
    part[tid] += v;
    __syncthreads();
  }
  int run = (tid == 0) ? 0 : part[tid - 1];
  for (int i = lo; i < hi; ++i) {
    int c = counts_cursor[i];
    offsets[i] = run;
    counts_cursor[i] = run;  // cursor for fill_kernel
    run += c;
  }
  if (tid == 1023) offsets[N] = run;  // == E
}

// ---------------------------------------------------------------------------
// CSR build step 3: place each edge id at cursor[dst]++.
// ---------------------------------------------------------------------------
__global__ void __launch_bounds__(256) fill_kernel(
    const int* __restrict__ dst, int* __restrict__ cursor,
    int* __restrict__ csr_eid, int E) {
  int i = blockIdx.x * 256 + threadIdx.x;
  if (i >= E) return;
  int pos = atomicAdd(&cursor[dst[i]], 1);
  csr_eid[pos] = i;
}

// ---------------------------------------------------------------------------
// Step 4: gather. One 64-lane wave per node; lane l owns floats [4l,4l+4).
// ---------------------------------------------------------------------------
__global__ void __launch_bounds__(256) gather_kernel(
    const float* __restrict__ feat, const int* __restrict__ offsets,
    const int* __restrict__ csr_eid, const int* __restrict__ src,
    const float* __restrict__ ew, float* __restrict__ out, int N) {
  int node = (blockIdx.x * 256 + threadIdx.x) >> 6;
  int lane = threadIdx.x & 63;
  if (node >= N) return;
  int e = offsets[node];
  const int end = offsets[node + 1];
  float4 acc = {0.f, 0.f, 0.f, 0.f};
  for (; e + 2 <= end; e += 2) {
    int i0 = csr_eid[e], i1 = csr_eid[e + 1];
    int s0 = src[i0], s1 = src[i1];
    float w0 = ew[i0], w1 = ew[i1];
    float4 v0 = *(const float4*)(feat + (size_t)s0 * D + lane * 4);
    float4 v1 = *(const float4*)(feat + (size_t)s1 * D + lane * 4);
    acc.x = fmaf(v0.x, w0, acc.x); acc.y = fmaf(v0.y, w0, acc.y);
    acc.z = fmaf(v0.z, w0, acc.z); acc.w = fmaf(v0.w, w0, acc.w);
    acc.x = fmaf(v1.x, w1, acc.x); acc.y = fmaf(v1.y, w1, acc.y);
    acc.z = fmaf(v1.z, w1, acc.z); acc.w = fmaf(v1.w, w1, acc.w);
  }
  if (e < end) {
    int i0 = csr_eid[e];
    int s0 = src[i0];
    float w0 = ew[i0];
    float4 v0 = *(const float4*)(feat + (size_t)s0 * D + lane * 4);
    acc.x = fmaf(v0.x, w0, acc.x); acc.y = fmaf(v0.y, w0, acc.y);
    acc.z = fmaf(v0.z, w0, acc.z); acc.w = fmaf(v0.w, w0, acc.w);
  }
  *(float4*)(out + (size_t)node * D + lane * 4) = acc;
}

// ---------------------------------------------------------------------------
// Fallback phase (only if ws too small): atomic scatter, one wave per edge.
// ---------------------------------------------------------------------------
__global__ void __launch_bounds__(256) scatter_edges(
    const float* __restrict__ feat, const int* __restrict__ src,
    const int* __restrict__ dst, const float* __restrict__ ew,
    float* __restrict__ agg, int E) {
  int gid = blockIdx.x * 256 + threadIdx.x;
  int e = gid >> 6;
  int lane = threadIdx.x & 63;
  if (e >= E) return;
  int s = src[e];
  int d = dst[e];
  float wt = ew[e];
  const float4 v = *(const float4*)(feat + (size_t)s * D + lane * 4);
  float* o = agg + (size_t)d * D + lane * 4;
  unsafeAtomicAdd(o + 0, v.x * wt);
  unsafeAtomicAdd(o + 1, v.y * wt);
  unsafeAtomicAdd(o + 2, v.z * wt);
  unsafeAtomicAdd(o + 3, v.w * wt);
}

// ---------------------------------------------------------------------------
// Step 5: in-place projection  row <- row @ W.T + b  via bf16 MFMA.
// Block = 256 threads = 4 waves; block owns 64 rows, wave w owns cols
// [64w, 64w+64). Fragments: mfma_f32_16x16x32_bf16, K-loop of 8.
// A-frag: lane l reads A[m0+mb*16+(l&15)][kk*32+(l>>4)*8 .. +8) (32B contig).
// B-frag element (k,n)=W[n][k]: lane l reads W[n0+nb*16+(l&15)][same k range].
// A wave covers 16 rows x 128B contiguous each -> fully coalesced.
// fp32 -> bf16 converted in flight (RNE); accumulate fp32. No LDS.
// In-place safe: block reads only the rows it writes; __syncthreads()
// separates the last A-read from the first store.
// ---------------------------------------------------------------------------
__device__ __forceinline__ short f2b(float f) {
  __hip_bfloat16 h = __float2bfloat16(f);
  return *reinterpret_cast<short*>(&h);
}

__device__ __forceinline__ bf16x8 load_cvt8(const float* p) {
  f32x4 a = *(const f32x4*)p;
  f32x4 b = *(const f32x4*)(p + 4);
  bf16x8 r;
  r[0] = f2b(a[0]); r[1] = f2b(a[1]); r[2] = f2b(a[2]); r[3] = f2b(a[3]);
  r[4] = f2b(b[0]); r[5] = f2b(b[1]); r[6] = f2b(b[2]); r[7] = f2b(b[3]);
  return r;
}

__global__ void __launch_bounds__(256) proj_mfma(
    float* __restrict__ io, const float* __restrict__ W,
    const float* __restrict__ bias, int M) {
  const int tid = threadIdx.x;
  const int wave = tid >> 6;
  const int lane = tid & 63;
  const int lrow = lane & 15;  // fragment row (A) / col (B,D)
  const int lkg = lane >> 4;   // k-group 0..3

  const int m0 = blockIdx.x * 64;
  const int n0 = wave * 64;

  f32x4 acc[4][4] = {};  // [mb][nb]

  const float* arow0;
  const float* arow1;
  const float* arow2;
  const float* arow3;
  {
    int r0 = min(m0 + 0 * 16 + lrow, M - 1);
    int r1 = min(m0 + 1 * 16 + lrow, M - 1);
    int r2 = min(m0 + 2 * 16 + lrow, M - 1);
    int r3 = min(m0 + 3 * 16 + lrow, M - 1);
    arow0 = io + (size_t)r0 * D + lkg * 8;
    arow1 = io + (size_t)r1 * D + lkg * 8;
    arow2 = io + (size_t)r2 * D + lkg * 8;
    arow3 = io + (size_t)r3 * D + lkg * 8;
  }
  const float* brow0 = W + (size_t)(n0 + 0 * 16 + lrow) * D + lkg * 8;
  const float* brow1 = W + (size_t)(n0 + 1 * 16 + lrow) * D + lkg * 8;
  const float* brow2 = W + (size_t)(n0 + 2 * 16 + lrow) * D + lkg * 8;
  const float* brow3 = W + (size_t)(n0 + 3 * 16 + lrow) * D + lkg * 8;

#pragma unroll
  for (int kk = 0; kk < 8; ++kk) {
    bf16x8 af[4], bf[4];
    af[0] = load_cvt8(arow0 + kk * 32);
    af[1] = load_cvt8(arow1 + kk * 32);
    af[2] = load_cvt8(arow2 + kk * 32);
    af[3] = load_cvt8(arow3 + kk * 32);
    bf[0] = load_cvt8(brow0 + kk * 32);
    bf[1] = load_cvt8(brow1 + kk * 32);
    bf[2] = load_cvt8(brow2 + kk * 32);
    bf[3] = load_cvt8(brow3 + kk * 32);
#pragma unroll
    for (int mb = 0; mb < 4; ++mb)
#pragma unroll
      for (int nb = 0; nb < 4; ++nb)
        acc[mb][nb] = __builtin_amdgcn_mfma_f32_16x16x32_bf16(
            af[mb], bf[nb], acc[mb][nb], 0, 0, 0);
  }

  // All A reads of this block are complete before any in-place store.
  __syncthreads();

  float bv[4];
#pragma unroll
  for (int nb = 0; nb < 4; ++nb) bv[nb] = bias[n0 + nb * 16 + lrow];

#pragma unroll
  for (int mb = 0; mb < 4; ++mb) {
#pragma unroll
    for (int reg = 0; reg < 4; ++reg) {
      int r = m0 + mb * 16 + lkg * 4 + reg;
      if (r < M) {
#pragma unroll
        for (int nb = 0; nb < 4; ++nb)
          io[(size_t)r * D + n0 + nb * 16 + lrow] = acc[mb][nb][reg] + bv[nb];
      }
    }
  }
}

extern "C" void kernel_launch(void* const* d_in, const int* in_sizes, int n_in,
                              void* d_out, int out_size, void* d_ws, size_t ws_size,
                              hipStream_t stream) {
  const float* feat = (const float*)d_in[0];
  const int* src = (const int*)d_in[1];
  const int* dst = (const int*)d_in[2];
  const float* ew = (const float*)d_in[3];
  const float* W = (const float*)d_in[4];
  const float* bias = (const float*)d_in[5];
  float* out = (float*)d_out;

  const int E = in_sizes[1];
  const int M = out_size / D;  // == N nodes

  // Workspace layout (256B-aligned sections):
  //   offsets : int[M+1]
  //   cursor  : int[M]      (doubles as counts)
  //   csr_eid : int[E]
  size_t off_b = ((size_t)(M + 1) * 4 + 255) & ~(size_t)255;
  size_t cur_b = ((size_t)M * 4 + 255) & ~(size_t)255;
  size_t eid_b = ((size_t)E * 4 + 255) & ~(size_t)255;
  size_t need = off_b + cur_b + eid_b;

  if (ws_size >= need && d_ws != nullptr) {
    char* ws = (char*)d_ws;
    int* offsets = (int*)ws;
    int* cursor = (int*)(ws + off_b);
    int* csr_eid = (int*)(ws + off_b + cur_b);

    const int eb = (E + 255) / 256;
    hipMemsetAsync(cursor, 0, (size_t)M * 4, stream);  // ws poisoned 0xAA
    hist_kernel<<<eb, 256, 0, stream>>>(dst, cursor, E);
    scan_kernel<<<1, 1024, 0, stream>>>(cursor, offsets, M);
    fill_kernel<<<eb, 256, 0, stream>>>(dst, cursor, csr_eid, E);

    long long threads = (long long)M * 64;
    int blocks = (int)((threads + 255) / 256);
    gather_kernel<<<blocks, 256, 0, stream>>>(feat, offsets, csr_eid, src, ew,
                                              out, M);
  } else {
    // Fallback: atomic-scatter path (no workspace needed).
    hipMemsetAsync(out, 0, (size_t)out_size * sizeof(float), stream);
    long long threads = (long long)E * 64;
    int blocks = (int)((threads + 255) / 256);
    scatter_edges<<<blocks, 256, 0, stream>>>(feat, src, dst, ew, out, E);
  }

  proj_mfma<<<(M + 63) / 64, 256, 0, stream>>>(out, W, bias, M);
}

// Round 10
// 691.332 us; speedup vs baseline: 8.6543x; 1.3807x over previous
//
#include <hip/hip_runtime.h>
#include <hip/hip_bf16.h>

#define D 256
#define SCAN_CHUNK 2048  // elements per scan block (256 thr x 8)

typedef __attribute__((ext_vector_type(8))) short bf16x8;
typedef __attribute__((ext_vector_type(4))) float f32x4;
typedef __attribute__((ext_vector_type(4))) unsigned short u16x4;
typedef __attribute__((ext_vector_type(8))) unsigned short u16x8;

// ---------------------------------------------------------------------------
// CSR build step 1: per-dst in-degree histogram (counts lives in cursor buf).
// ---------------------------------------------------------------------------
__global__ void __launch_bounds__(256) hist_kernel(
    const int* __restrict__ dst, int* __restrict__ counts, int E) {
  int i = blockIdx.x * 256 + threadIdx.x;
  if (i < E) atomicAdd(&counts[dst[i]], 1);
}

// ---------------------------------------------------------------------------
// Parallel exclusive scan, 3 phases. Old single-block scan was ~1 CU doing
// 800KB latency-bound work (suspected ~500us). Now: 49 blocks.
// Phase A: per-chunk sums.
// ---------------------------------------------------------------------------
__global__ void __launch_bounds__(256) scan_chunk_sum(
    const int* __restrict__ counts, int* __restrict__ chunk_sum, int N) {
  __shared__ int lds[256];
  const int t = threadIdx.x;
  const int base = blockIdx.x * SCAN_CHUNK + t * 8;
  int s = 0;
#pragma unroll
  for (int j = 0; j < 8; ++j) {
    int i = base + j;
    if (i < N) s += counts[i];
  }
  lds[t] = s;
  __syncthreads();
  for (int off = 128; off > 0; off >>= 1) {
    if (t < off) lds[t] += lds[t + off];
    __syncthreads();
  }
  if (t == 0) chunk_sum[blockIdx.x] = lds[0];
}

// Phase B: exclusive scan of the (few) chunk sums; also writes offsets[N]=E.
__global__ void __launch_bounds__(64) scan_chunk_off(
    const int* __restrict__ chunk_sum, int* __restrict__ chunk_off, int NC,
    int* __restrict__ offsets, int N, int E) {
  if (threadIdx.x == 0) {
    int run = 0;
    for (int c = 0; c < NC; ++c) {
      chunk_off[c] = run;
      run += chunk_sum[c];
    }
    offsets[N] = E;
  }
}

// Phase C: per-chunk exclusive scan -> offsets + cursor. In-place safe:
// each thread reads its own 8 counts before overwriting them.
__global__ void __launch_bounds__(256) scan_finalize(
    int* __restrict__ counts_cursor, int* __restrict__ offsets,
    const int* __restrict__ chunk_off, int N) {
  __shared__ int lds[256];
  const int t = threadIdx.x;
  const int base_i = blockIdx.x * SCAN_CHUNK + t * 8;
  int c[8];
  int s = 0;
#pragma unroll
  for (int j = 0; j < 8; ++j) {
    int i = base_i + j;
    c[j] = (i < N) ? counts_cursor[i] : 0;
    s += c[j];
  }
  lds[t] = s;
  __syncthreads();
  for (int off = 1; off < 256; off <<= 1) {
    int v = (t >= off) ? lds[t - off] : 0;
    __syncthreads();
    lds[t] += v;
    __syncthreads();
  }
  int run = chunk_off[blockIdx.x] + ((t > 0) ? lds[t - 1] : 0);
#pragma unroll
  for (int j = 0; j < 8; ++j) {
    int i = base_i + j;
    if (i < N) {
      offsets[i] = run;
      counts_cursor[i] = run;  // cursor for fill_kernel
      run += c[j];
    }
  }
}

// ---------------------------------------------------------------------------
// CSR build step 3: place each edge id at cursor[dst]++.
// ---------------------------------------------------------------------------
__global__ void __launch_bounds__(256) fill_kernel(
    const int* __restrict__ dst, int* __restrict__ cursor,
    int* __restrict__ csr_eid, int E) {
  int i = blockIdx.x * 256 + threadIdx.x;
  if (i >= E) return;
  int pos = atomicAdd(&cursor[dst[i]], 1);
  csr_eid[pos] = i;
}

// ---------------------------------------------------------------------------
// Feature fp32 -> bf16 staging (halves gather read bytes). RNE, same
// rounding as proj's in-flight conversion. 8 elems/thread.
// ---------------------------------------------------------------------------
__device__ __forceinline__ unsigned short f2b_u(float f) {
  __hip_bfloat16 h = __float2bfloat16(f);
  return *reinterpret_cast<unsigned short*>(&h);
}

__global__ void __launch_bounds__(256) cvt_feat_kernel(
    const float* __restrict__ feat, unsigned short* __restrict__ fb,
    long long n) {  // n multiple of 8
  long long i = ((long long)blockIdx.x * 256 + threadIdx.x) * 8;
  if (i >= n) return;
  f32x4 a = *(const f32x4*)(feat + i);
  f32x4 b = *(const f32x4*)(feat + i + 4);
  u16x8 r;
  r[0] = f2b_u(a[0]); r[1] = f2b_u(a[1]); r[2] = f2b_u(a[2]); r[3] = f2b_u(a[3]);
  r[4] = f2b_u(b[0]); r[5] = f2b_u(b[1]); r[6] = f2b_u(b[2]); r[7] = f2b_u(b[3]);
  *(u16x8*)(fb + i) = r;
}

// ---------------------------------------------------------------------------
// Gather (bf16 features). One wave per node; lane l owns dims [4l,4l+4).
// 8B/lane row reads (512B/row), fp32 accumulate, exact bits<<16 decode.
// ---------------------------------------------------------------------------
__device__ __forceinline__ float b2f(unsigned short u) {
  unsigned int x = ((unsigned int)u) << 16;
  return __builtin_bit_cast(float, x);
}

__global__ void __launch_bounds__(256) gather_bf16_kernel(
    const unsigned short* __restrict__ fb, const int* __restrict__ offsets,
    const int* __restrict__ csr_eid, const int* __restrict__ src,
    const float* __restrict__ ew, float* __restrict__ out, int N) {
  int node = (blockIdx.x * 256 + threadIdx.x) >> 6;
  int lane = threadIdx.x & 63;
  if (node >= N) return;
  int e = offsets[node];
  const int end = offsets[node + 1];
  float4 acc = {0.f, 0.f, 0.f, 0.f};
  for (; e + 2 <= end; e += 2) {
    int i0 = csr_eid[e], i1 = csr_eid[e + 1];
    int s0 = src[i0], s1 = src[i1];
    float w0 = ew[i0], w1 = ew[i1];
    u16x4 v0 = *(const u16x4*)(fb + (size_t)s0 * D + lane * 4);
    u16x4 v1 = *(const u16x4*)(fb + (size_t)s1 * D + lane * 4);
    acc.x = fmaf(b2f(v0[0]), w0, acc.x); acc.y = fmaf(b2f(v0[1]), w0, acc.y);
    acc.z = fmaf(b2f(v0[2]), w0, acc.z); acc.w = fmaf(b2f(v0[3]), w0, acc.w);
    acc.x = fmaf(b2f(v1[0]), w1, acc.x); acc.y = fmaf(b2f(v1[1]), w1, acc.y);
    acc.z = fmaf(b2f(v1[2]), w1, acc.z); acc.w = fmaf(b2f(v1[3]), w1, acc.w);
  }
  if (e < end) {
    int i0 = csr_eid[e];
    int s0 = src[i0];
    float w0 = ew[i0];
    u16x4 v0 = *(const u16x4*)(fb + (size_t)s0 * D + lane * 4);
    acc.x = fmaf(b2f(v0[0]), w0, acc.x); acc.y = fmaf(b2f(v0[1]), w0, acc.y);
    acc.z = fmaf(b2f(v0[2]), w0, acc.z); acc.w = fmaf(b2f(v0[3]), w0, acc.w);
  }
  *(float4*)(out + (size_t)node * D + lane * 4) = acc;
}

// ---------------------------------------------------------------------------
// Gather (fp32 features) — tier-2 path if ws can't hold bf16 staging.
// ---------------------------------------------------------------------------
__global__ void __launch_bounds__(256) gather_kernel(
    const float* __restrict__ feat, const int* __restrict__ offsets,
    const int* __restrict__ csr_eid, const int* __restrict__ src,
    const float* __restrict__ ew, float* __restrict__ out, int N) {
  int node = (blockIdx.x * 256 + threadIdx.x) >> 6;
  int lane = threadIdx.x & 63;
  if (node >= N) return;
  int e = offsets[node];
  const int end = offsets[node + 1];
  float4 acc = {0.f, 0.f, 0.f, 0.f};
  for (; e + 2 <= end; e += 2) {
    int i0 = csr_eid[e], i1 = csr_eid[e + 1];
    int s0 = src[i0], s1 = src[i1];
    float w0 = ew[i0], w1 = ew[i1];
    float4 v0 = *(const float4*)(feat + (size_t)s0 * D + lane * 4);
    float4 v1 = *(const float4*)(feat + (size_t)s1 * D + lane * 4);
    acc.x = fmaf(v0.x, w0, acc.x); acc.y = fmaf(v0.y, w0, acc.y);
    acc.z = fmaf(v0.z, w0, acc.z); acc.w = fmaf(v0.w, w0, acc.w);
    acc.x = fmaf(v1.x, w1, acc.x); acc.y = fmaf(v1.y, w1, acc.y);
    acc.z = fmaf(v1.z, w1, acc.z); acc.w = fmaf(v1.w, w1, acc.w);
  }
  if (e < end) {
    int i0 = csr_eid[e];
    int s0 = src[i0];
    float w0 = ew[i0];
    float4 v0 = *(const float4*)(feat + (size_t)s0 * D + lane * 4);
    acc.x = fmaf(v0.x, w0, acc.x); acc.y = fmaf(v0.y, w0, acc.y);
    acc.z = fmaf(v0.z, w0, acc.z); acc.w = fmaf(v0.w, w0, acc.w);
  }
  *(float4*)(out + (size_t)node * D + lane * 4) = acc;
}

// ---------------------------------------------------------------------------
// Fallback (ws too small even for CSR): atomic scatter, one wave per edge.
// ---------------------------------------------------------------------------
__global__ void __launch_bounds__(256) scatter_edges(
    const float* __restrict__ feat, const int* __restrict__ src,
    const int* __restrict__ dst, const float* __restrict__ ew,
    float* __restrict__ agg, int E) {
  int gid = blockIdx.x * 256 + threadIdx.x;
  int e = gid >> 6;
  int lane = threadIdx.x & 63;
  if (e >= E) return;
  int s = src[e];
  int d = dst[e];
  float wt = ew[e];
  const float4 v = *(const float4*)(feat + (size_t)s * D + lane * 4);
  float* o = agg + (size_t)d * D + lane * 4;
  unsafeAtomicAdd(o + 0, v.x * wt);
  unsafeAtomicAdd(o + 1, v.y * wt);
  unsafeAtomicAdd(o + 2, v.z * wt);
  unsafeAtomicAdd(o + 3, v.w * wt);
}

// ---------------------------------------------------------------------------
// Projection  row <- row @ W.T + b  via bf16 MFMA (in-place, no LDS).
// Verified correct in R7 (absmax 0.031).
// ---------------------------------------------------------------------------
__device__ __forceinline__ short f2b(float f) {
  __hip_bfloat16 h = __float2bfloat16(f);
  return *reinterpret_cast<short*>(&h);
}

__device__ __forceinline__ bf16x8 load_cvt8(const float* p) {
  f32x4 a = *(const f32x4*)p;
  f32x4 b = *(const f32x4*)(p + 4);
  bf16x8 r;
  r[0] = f2b(a[0]); r[1] = f2b(a[1]); r[2] = f2b(a[2]); r[3] = f2b(a[3]);
  r[4] = f2b(b[0]); r[5] = f2b(b[1]); r[6] = f2b(b[2]); r[7] = f2b(b[3]);
  return r;
}

__global__ void __launch_bounds__(256) proj_mfma(
    float* __restrict__ io, const float* __restrict__ W,
    const float* __restrict__ bias, int M) {
  const int tid = threadIdx.x;
  const int wave = tid >> 6;
  const int lane = tid & 63;
  const int lrow = lane & 15;
  const int lkg = lane >> 4;

  const int m0 = blockIdx.x * 64;
  const int n0 = wave * 64;

  f32x4 acc[4][4] = {};

  const float* arow0;
  const float* arow1;
  const float* arow2;
  const float* arow3;
  {
    int r0 = min(m0 + 0 * 16 + lrow, M - 1);
    int r1 = min(m0 + 1 * 16 + lrow, M - 1);
    int r2 = min(m0 + 2 * 16 + lrow, M - 1);
    int r3 = min(m0 + 3 * 16 + lrow, M - 1);
    arow0 = io + (size_t)r0 * D + lkg * 8;
    arow1 = io + (size_t)r1 * D + lkg * 8;
    arow2 = io + (size_t)r2 * D + lkg * 8;
    arow3 = io + (size_t)r3 * D + lkg * 8;
  }
  const float* brow0 = W + (size_t)(n0 + 0 * 16 + lrow) * D + lkg * 8;
  const float* brow1 = W + (size_t)(n0 + 1 * 16 + lrow) * D + lkg * 8;
  const float* brow2 = W + (size_t)(n0 + 2 * 16 + lrow) * D + lkg * 8;
  const float* brow3 = W + (size_t)(n0 + 3 * 16 + lrow) * D + lkg * 8;

#pragma unroll
  for (int kk = 0; kk < 8; ++kk) {
    bf16x8 af[4], bf[4];
    af[0] = load_cvt8(arow0 + kk * 32);
    af[1] = load_cvt8(arow1 + kk * 32);
    af[2] = load_cvt8(arow2 + kk * 32);
    af[3] = load_cvt8(arow3 + kk * 32);
    bf[0] = load_cvt8(brow0 + kk * 32);
    bf[1] = load_cvt8(brow1 + kk * 32);
    bf[2] = load_cvt8(brow2 + kk * 32);
    bf[3] = load_cvt8(brow3 + kk * 32);
#pragma unroll
    for (int mb = 0; mb < 4; ++mb)
#pragma unroll
      for (int nb = 0; nb < 4; ++nb)
        acc[mb][nb] = __builtin_amdgcn_mfma_f32_16x16x32_bf16(
            af[mb], bf[nb], acc[mb][nb], 0, 0, 0);
  }

  __syncthreads();  // all A reads done before in-place stores

  float bv[4];
#pragma unroll
  for (int nb = 0; nb < 4; ++nb) bv[nb] = bias[n0 + nb * 16 + lrow];

#pragma unroll
  for (int mb = 0; mb < 4; ++mb) {
#pragma unroll
    for (int reg = 0; reg < 4; ++reg) {
      int r = m0 + mb * 16 + lkg * 4 + reg;
      if (r < M) {
#pragma unroll
        for (int nb = 0; nb < 4; ++nb)
          io[(size_t)r * D + n0 + nb * 16 + lrow] = acc[mb][nb][reg] + bv[nb];
      }
    }
  }
}

extern "C" void kernel_launch(void* const* d_in, const int* in_sizes, int n_in,
                              void* d_out, int out_size, void* d_ws, size_t ws_size,
                              hipStream_t stream) {
  const float* feat = (const float*)d_in[0];
  const int* src = (const int*)d_in[1];
  const int* dst = (const int*)d_in[2];
  const float* ew = (const float*)d_in[3];
  const float* W = (const float*)d_in[4];
  const float* bias = (const float*)d_in[5];
  float* out = (float*)d_out;

  const int E = in_sizes[1];
  const int M = out_size / D;               // nodes
  const long long nfeat = in_sizes[0];      // feature element count (M*D)
  const int NC = (M + SCAN_CHUNK - 1) / SCAN_CHUNK;

  // ws layout: offsets[M+1] | cursor[M] | csr_eid[E] | chunk[2*NC] | fb[nfeat]
  size_t off_b = ((size_t)(M + 1) * 4 + 255) & ~(size_t)255;
  size_t cur_b = ((size_t)M * 4 + 255) & ~(size_t)255;
  size_t eid_b = ((size_t)E * 4 + 255) & ~(size_t)255;
  size_t chk_b = ((size_t)(2 * NC) * 4 + 255) & ~(size_t)255;
  size_t fb_b = ((size_t)nfeat * 2 + 255) & ~(size_t)255;
  size_t need_csr = off_b + cur_b + eid_b + chk_b;
  size_t need_bf16 = need_csr + fb_b;

  if (ws_size >= need_csr && d_ws != nullptr) {
    char* ws = (char*)d_ws;
    int* offsets = (int*)ws;
    int* cursor = (int*)(ws + off_b);
    int* csr_eid = (int*)(ws + off_b + cur_b);
    int* chunk_sum = (int*)(ws + off_b + cur_b + eid_b);
    int* chunk_off = chunk_sum + NC;
    unsigned short* fb = (unsigned short*)(ws + need_csr);

    const int eb = (E + 255) / 256;
    const bool use_bf16 = (ws_size >= need_bf16);

    // Stage bf16 features first (independent of CSR build, overlaps nothing
    // but keeps the graph simple).
    if (use_bf16) {
      int cb = (int)((nfeat / 8 + 255) / 256);
      cvt_feat_kernel<<<cb, 256, 0, stream>>>(feat, fb, nfeat);
    }

    hipMemsetAsync(cursor, 0, (size_t)M * 4, stream);  // ws poisoned 0xAA
    hist_kernel<<<eb, 256, 0, stream>>>(dst, cursor, E);
    scan_chunk_sum<<<NC, 256, 0, stream>>>(cursor, chunk_sum, M);
    scan_chunk_off<<<1, 64, 0, stream>>>(chunk_sum, chunk_off, NC, offsets, M, E);
    scan_finalize<<<NC, 256, 0, stream>>>(cursor, offsets, chunk_off, M);
    fill_kernel<<<eb, 256, 0, stream>>>(dst, cursor, csr_eid, E);

    long long threads = (long long)M * 64;
    int blocks = (int)((threads + 255) / 256);
    if (use_bf16) {
      gather_bf16_kernel<<<blocks, 256, 0, stream>>>(fb, offsets, csr_eid, src,
                                                     ew, out, M);
    } else {
      gather_kernel<<<blocks, 256, 0, stream>>>(feat, offsets, csr_eid, src,
                                                ew, out, M);
    }
  } else {
    // Fallback: atomic-scatter path (no workspace needed).
    hipMemsetAsync(out, 0, (size_t)out_size * sizeof(float), stream);
    long long threads = (long long)E * 64;
    int blocks = (int)((threads + 255) / 256);
    scatter_edges<<<blocks, 256, 0, stream>>>(feat, src, dst, ew, out, E);
  }

  proj_mfma<<<(M + 63) / 64, 256, 0, stream>>>(out, W, bias, M);
}

// Round 12
// 573.452 us; speedup vs baseline: 10.4333x; 1.2056x over previous
//
#include <hip/hip_runtime.h>
#include <hip/hip_bf16.h>

#define D 256
#define SCAN_CHUNK 2048  // elements per scan block (256 thr x 8)

typedef __attribute__((ext_vector_type(8))) short bf16x8;
typedef __attribute__((ext_vector_type(4))) float f32x4;
typedef __attribute__((ext_vector_type(4))) unsigned short u16x4;
typedef __attribute__((ext_vector_type(8))) unsigned short u16x8;

// ---------------------------------------------------------------------------
// CSR build step 1: per-dst in-degree histogram (counts lives in cursor buf).
// ---------------------------------------------------------------------------
__global__ void __launch_bounds__(256) hist_kernel(
    const int* __restrict__ dst, int* __restrict__ counts, int E) {
  int i = blockIdx.x * 256 + threadIdx.x;
  if (i < E) atomicAdd(&counts[dst[i]], 1);
}

// ---------------------------------------------------------------------------
// Parallel exclusive scan, 3 phases (R10-verified).
// ---------------------------------------------------------------------------
__global__ void __launch_bounds__(256) scan_chunk_sum(
    const int* __restrict__ counts, int* __restrict__ chunk_sum, int N) {
  __shared__ int lds[256];
  const int t = threadIdx.x;
  const int base = blockIdx.x * SCAN_CHUNK + t * 8;
  int s = 0;
#pragma unroll
  for (int j = 0; j < 8; ++j) {
    int i = base + j;
    if (i < N) s += counts[i];
  }
  lds[t] = s;
  __syncthreads();
  for (int off = 128; off > 0; off >>= 1) {
    if (t < off) lds[t] += lds[t + off];
    __syncthreads();
  }
  if (t == 0) chunk_sum[blockIdx.x] = lds[0];
}

__global__ void __launch_bounds__(64) scan_chunk_off(
    const int* __restrict__ chunk_sum, int* __restrict__ chunk_off, int NC,
    int* __restrict__ offsets, int N, int E) {
  if (threadIdx.x == 0) {
    int run = 0;
    for (int c = 0; c < NC; ++c) {
      chunk_off[c] = run;
      run += chunk_sum[c];
    }
    offsets[N] = E;
  }
}

__global__ void __launch_bounds__(256) scan_finalize(
    int* __restrict__ counts_cursor, int* __restrict__ offsets,
    const int* __restrict__ chunk_off, int N) {
  __shared__ int lds[256];
  const int t = threadIdx.x;
  const int base_i = blockIdx.x * SCAN_CHUNK + t * 8;
  int c[8];
  int s = 0;
#pragma unroll
  for (int j = 0; j < 8; ++j) {
    int i = base_i + j;
    c[j] = (i < N) ? counts_cursor[i] : 0;
    s += c[j];
  }
  lds[t] = s;
  __syncthreads();
  for (int off = 1; off < 256; off <<= 1) {
    int v = (t >= off) ? lds[t - off] : 0;
    __syncthreads();
    lds[t] += v;
    __syncthreads();
  }
  int run = chunk_off[blockIdx.x] + ((t > 0) ? lds[t - 1] : 0);
#pragma unroll
  for (int j = 0; j < 8; ++j) {
    int i = base_i + j;
    if (i < N) {
      offsets[i] = run;
      counts_cursor[i] = run;  // cursor for fill
      run += c[j];
    }
  }
}

// ---------------------------------------------------------------------------
// CSR fill, tier A: place packed {src, w_bits} at cursor[dst]++ (8B write).
// Removes the eid->src/ew dependent-load level from the gather.
// ---------------------------------------------------------------------------
__global__ void __launch_bounds__(256) fill_pair_kernel(
    const int* __restrict__ src, const int* __restrict__ dst,
    const float* __restrict__ ew, int* __restrict__ cursor,
    int2* __restrict__ pairs, int E) {
  int i = blockIdx.x * 256 + threadIdx.x;
  if (i >= E) return;
  int pos = atomicAdd(&cursor[dst[i]], 1);
  pairs[pos] = make_int2(src[i], __float_as_int(ew[i]));
}

// CSR fill, tier B: edge-id only (R10-verified).
__global__ void __launch_bounds__(256) fill_kernel(
    const int* __restrict__ dst, int* __restrict__ cursor,
    int* __restrict__ csr_eid, int E) {
  int i = blockIdx.x * 256 + threadIdx.x;
  if (i >= E) return;
  int pos = atomicAdd(&cursor[dst[i]], 1);
  csr_eid[pos] = i;
}

// ---------------------------------------------------------------------------
// bf16 helpers.
// ---------------------------------------------------------------------------
__device__ __forceinline__ unsigned short f2b_u(float f) {
  __hip_bfloat16 h = __float2bfloat16(f);
  return *reinterpret_cast<unsigned short*>(&h);
}
__device__ __forceinline__ short f2b(float f) {
  __hip_bfloat16 h = __float2bfloat16(f);
  return *reinterpret_cast<short*>(&h);
}
__device__ __forceinline__ float b2f(unsigned short u) {
  unsigned int x = ((unsigned int)u) << 16;
  return __builtin_bit_cast(float, x);
}
__device__ __forceinline__ bf16x8 load_cvt8(const float* p) {
  f32x4 a = *(const f32x4*)p;
  f32x4 b = *(const f32x4*)(p + 4);
  bf16x8 r;
  r[0] = f2b(a[0]); r[1] = f2b(a[1]); r[2] = f2b(a[2]); r[3] = f2b(a[3]);
  r[4] = f2b(b[0]); r[5] = f2b(b[1]); r[6] = f2b(b[2]); r[7] = f2b(b[3]);
  return r;
}

// ---------------------------------------------------------------------------
// Tier A step 1: Y = X @ W.T (bf16 out), MFMA. Same fragment scheme as the
// R7-verified proj_mfma, but reads feat and writes bf16 Y (no bias here;
// bias is added in the gather epilogue — linearity reorder).
// ---------------------------------------------------------------------------
__global__ void __launch_bounds__(256) proj_feat_mfma(
    const float* __restrict__ feat, const float* __restrict__ W,
    unsigned short* __restrict__ Y, int M) {
  const int tid = threadIdx.x;
  const int wave = tid >> 6;
  const int lane = tid & 63;
  const int lrow = lane & 15;
  const int lkg = lane >> 4;

  const int m0 = blockIdx.x * 64;
  const int n0 = wave * 64;

  f32x4 acc[4][4] = {};

  const float* arow0;
  const float* arow1;
  const float* arow2;
  const float* arow3;
  {
    int r0 = min(m0 + 0 * 16 + lrow, M - 1);
    int r1 = min(m0 + 1 * 16 + lrow, M - 1);
    int r2 = min(m0 + 2 * 16 + lrow, M - 1);
    int r3 = min(m0 + 3 * 16 + lrow, M - 1);
    arow0 = feat + (size_t)r0 * D + lkg * 8;
    arow1 = feat + (size_t)r1 * D + lkg * 8;
    arow2 = feat + (size_t)r2 * D + lkg * 8;
    arow3 = feat + (size_t)r3 * D + lkg * 8;
  }
  const float* brow0 = W + (size_t)(n0 + 0 * 16 + lrow) * D + lkg * 8;
  const float* brow1 = W + (size_t)(n0 + 1 * 16 + lrow) * D + lkg * 8;
  const float* brow2 = W + (size_t)(n0 + 2 * 16 + lrow) * D + lkg * 8;
  const float* brow3 = W + (size_t)(n0 + 3 * 16 + lrow) * D + lkg * 8;

#pragma unroll
  for (int kk = 0; kk < 8; ++kk) {
    bf16x8 af[4], bf[4];
    af[0] = load_cvt8(arow0 + kk * 32);
    af[1] = load_cvt8(arow1 + kk * 32);
    af[2] = load_cvt8(arow2 + kk * 32);
    af[3] = load_cvt8(arow3 + kk * 32);
    bf[0] = load_cvt8(brow0 + kk * 32);
    bf[1] = load_cvt8(brow1 + kk * 32);
    bf[2] = load_cvt8(brow2 + kk * 32);
    bf[3] = load_cvt8(brow3 + kk * 32);
#pragma unroll
    for (int mb = 0; mb < 4; ++mb)
#pragma unroll
      for (int nb = 0; nb < 4; ++nb)
        acc[mb][nb] = __builtin_amdgcn_mfma_f32_16x16x32_bf16(
            af[mb], bf[nb], acc[mb][nb], 0, 0, 0);
  }

#pragma unroll
  for (int mb = 0; mb < 4; ++mb) {
#pragma unroll
    for (int reg = 0; reg < 4; ++reg) {
      int r = m0 + mb * 16 + lkg * 4 + reg;
      if (r < M) {
#pragma unroll
        for (int nb = 0; nb < 4; ++nb)
          Y[(size_t)r * D + n0 + nb * 16 + lrow] = f2b_u(acc[mb][nb][reg]);
      }
    }
  }
}

// ---------------------------------------------------------------------------
// Tier A step 2: gather over projected bf16 rows + bias.
// HALF-WAVE per node: 32 lanes x 16B (u16x8) = one 512B row per load.
// Packed pairs: one 8B load gives (src, w) — no eid indirection.
// 4-deep unroll for memory-level parallelism. out = acc + bias (complete
// per-row write; empty-degree nodes correctly get out = bias).
// ---------------------------------------------------------------------------
__global__ void __launch_bounds__(256) gather_pair_kernel(
    const unsigned short* __restrict__ Y, const int* __restrict__ offsets,
    const int2* __restrict__ pairs, const float* __restrict__ bias,
    float* __restrict__ out, int N) {
  int node = (blockIdx.x * 256 + threadIdx.x) >> 5;
  int sub = threadIdx.x & 31;  // owns dims [8*sub, 8*sub+8)
  if (node >= N) return;
  int e = offsets[node];
  const int end = offsets[node + 1];
  float acc[8] = {0.f, 0.f, 0.f, 0.f, 0.f, 0.f, 0.f, 0.f};
  const int d0 = sub * 8;

  for (; e + 4 <= end; e += 4) {
    int2 p0 = pairs[e + 0];
    int2 p1 = pairs[e + 1];
    int2 p2 = pairs[e + 2];
    int2 p3 = pairs[e + 3];
    u16x8 v0 = *(const u16x8*)(Y + (size_t)p0.x * D + d0);
    u16x8 v1 = *(const u16x8*)(Y + (size_t)p1.x * D + d0);
    u16x8 v2 = *(const u16x8*)(Y + (size_t)p2.x * D + d0);
    u16x8 v3 = *(const u16x8*)(Y + (size_t)p3.x * D + d0);
    float w0 = __int_as_float(p0.y);
    float w1 = __int_as_float(p1.y);
    float w2 = __int_as_float(p2.y);
    float w3 = __int_as_float(p3.y);
#pragma unroll
    for (int j = 0; j < 8; ++j) {
      acc[j] = fmaf(b2f(v0[j]), w0, acc[j]);
      acc[j] = fmaf(b2f(v1[j]), w1, acc[j]);
      acc[j] = fmaf(b2f(v2[j]), w2, acc[j]);
      acc[j] = fmaf(b2f(v3[j]), w3, acc[j]);
    }
  }
  for (; e < end; ++e) {
    int2 p0 = pairs[e];
    u16x8 v0 = *(const u16x8*)(Y + (size_t)p0.x * D + d0);
    float w0 = __int_as_float(p0.y);
#pragma unroll
    for (int j = 0; j < 8; ++j) acc[j] = fmaf(b2f(v0[j]), w0, acc[j]);
  }

  f32x4 bv0 = *(const f32x4*)(bias + d0);
  f32x4 bv1 = *(const f32x4*)(bias + d0 + 4);
  float* o = out + (size_t)node * D + d0;
  f32x4 r0 = {acc[0] + bv0[0], acc[1] + bv0[1], acc[2] + bv0[2], acc[3] + bv0[3]};
  f32x4 r1 = {acc[4] + bv1[0], acc[5] + bv1[1], acc[6] + bv1[2], acc[7] + bv1[3]};
  *(f32x4*)o = r0;
  *(f32x4*)(o + 4) = r1;
}

// ---------------------------------------------------------------------------
// Tier B kernels (R10-verified path): cvt + eid gather; proj after.
// ---------------------------------------------------------------------------
__global__ void __launch_bounds__(256) cvt_feat_kernel(
    const float* __restrict__ feat, unsigned short* __restrict__ fb,
    long long n) {
  long long i = ((long long)blockIdx.x * 256 + threadIdx.x) * 8;
  if (i >= n) return;
  f32x4 a = *(const f32x4*)(feat + i);
  f32x4 b = *(const f32x4*)(feat + i + 4);
  u16x8 r;
  r[0] = f2b_u(a[0]); r[1] = f2b_u(a[1]); r[2] = f2b_u(a[2]); r[3] = f2b_u(a[3]);
  r[4] = f2b_u(b[0]); r[5] = f2b_u(b[1]); r[6] = f2b_u(b[2]); r[7] = f2b_u(b[3]);
  *(u16x8*)(fb + i) = r;
}

__global__ void __launch_bounds__(256) gather_bf16_kernel(
    const unsigned short* __restrict__ fb, const int* __restrict__ offsets,
    const int* __restrict__ csr_eid, const int* __restrict__ src,
    const float* __restrict__ ew, float* __restrict__ out, int N) {
  int node = (blockIdx.x * 256 + threadIdx.x) >> 6;
  int lane = threadIdx.x & 63;
  if (node >= N) return;
  int e = offsets[node];
  const int end = offsets[node + 1];
  float4 acc = {0.f, 0.f, 0.f, 0.f};
  for (; e + 2 <= end; e += 2) {
    int i0 = csr_eid[e], i1 = csr_eid[e + 1];
    int s0 = src[i0], s1 = src[i1];
    float w0 = ew[i0], w1 = ew[i1];
    u16x4 v0 = *(const u16x4*)(fb + (size_t)s0 * D + lane * 4);
    u16x4 v1 = *(const u16x4*)(fb + (size_t)s1 * D + lane * 4);
    acc.x = fmaf(b2f(v0[0]), w0, acc.x); acc.y = fmaf(b2f(v0[1]), w0, acc.y);
    acc.z = fmaf(b2f(v0[2]), w0, acc.z); acc.w = fmaf(b2f(v0[3]), w0, acc.w);
    acc.x = fmaf(b2f(v1[0]), w1, acc.x); acc.y = fmaf(b2f(v1[1]), w1, acc.y);
    acc.z = fmaf(b2f(v1[2]), w1, acc.z); acc.w = fmaf(b2f(v1[3]), w1, acc.w);
  }
  if (e < end) {
    int i0 = csr_eid[e];
    int s0 = src[i0];
    float w0 = ew[i0];
    u16x4 v0 = *(const u16x4*)(fb + (size_t)s0 * D + lane * 4);
    acc.x = fmaf(b2f(v0[0]), w0, acc.x); acc.y = fmaf(b2f(v0[1]), w0, acc.y);
    acc.z = fmaf(b2f(v0[2]), w0, acc.z); acc.w = fmaf(b2f(v0[3]), w0, acc.w);
  }
  *(float4*)(out + (size_t)node * D + lane * 4) = acc;
}

// Tier C: fp32 gather (no staging).
__global__ void __launch_bounds__(256) gather_kernel(
    const float* __restrict__ feat, const int* __restrict__ offsets,
    const int* __restrict__ csr_eid, const int* __restrict__ src,
    const float* __restrict__ ew, float* __restrict__ out, int N) {
  int node = (blockIdx.x * 256 + threadIdx.x) >> 6;
  int lane = threadIdx.x & 63;
  if (node >= N) return;
  int e = offsets[node];
  const int end = offsets[node + 1];
  float4 acc = {0.f, 0.f, 0.f, 0.f};
  for (; e + 2 <= end; e += 2) {
    int i0 = csr_eid[e], i1 = csr_eid[e + 1];
    int s0 = src[i0], s1 = src[i1];
    float w0 = ew[i0], w1 = ew[i1];
    float4 v0 = *(const float4*)(feat + (size_t)s0 * D + lane * 4);
    float4 v1 = *(const float4*)(feat + (size_t)s1 * D + lane * 4);
    acc.x = fmaf(v0.x, w0, acc.x); acc.y = fmaf(v0.y, w0, acc.y);
    acc.z = fmaf(v0.z, w0, acc.z); acc.w = fmaf(v0.w, w0, acc.w);
    acc.x = fmaf(v1.x, w1, acc.x); acc.y = fmaf(v1.y, w1, acc.y);
    acc.z = fmaf(v1.z, w1, acc.z); acc.w = fmaf(v1.w, w1, acc.w);
  }
  if (e < end) {
    int i0 = csr_eid[e];
    int s0 = src[i0];
    float w0 = ew[i0];
    float4 v0 = *(const float4*)(feat + (size_t)s0 * D + lane * 4);
    acc.x = fmaf(v0.x, w0, acc.x); acc.y = fmaf(v0.y, w0, acc.y);
    acc.z = fmaf(v0.z, w0, acc.z); acc.w = fmaf(v0.w, w0, acc.w);
  }
  *(float4*)(out + (size_t)node * D + lane * 4) = acc;
}

// Tier D: atomic scatter.
__global__ void __launch_bounds__(256) scatter_edges(
    const float* __restrict__ feat, const int* __restrict__ src,
    const int* __restrict__ dst, const float* __restrict__ ew,
    float* __restrict__ agg, int E) {
  int gid = blockIdx.x * 256 + threadIdx.x;
  int e = gid >> 6;
  int lane = threadIdx.x & 63;
  if (e >= E) return;
  int s = src[e];
  int d = dst[e];
  float wt = ew[e];
  const float4 v = *(const float4*)(feat + (size_t)s * D + lane * 4);
  float* o = agg + (size_t)d * D + lane * 4;
  unsafeAtomicAdd(o + 0, v.x * wt);
  unsafeAtomicAdd(o + 1, v.y * wt);
  unsafeAtomicAdd(o + 2, v.z * wt);
  unsafeAtomicAdd(o + 3, v.w * wt);
}

// ---------------------------------------------------------------------------
// In-place projection out <- out @ W.T + b (tiers B/C/D only; R7-verified).
// ---------------------------------------------------------------------------
__global__ void __launch_bounds__(256) proj_mfma(
    float* __restrict__ io, const float* __restrict__ W,
    const float* __restrict__ bias, int M) {
  const int tid = threadIdx.x;
  const int wave = tid >> 6;
  const int lane = tid & 63;
  const int lrow = lane & 15;
  const int lkg = lane >> 4;

  const int m0 = blockIdx.x * 64;
  const int n0 = wave * 64;

  f32x4 acc[4][4] = {};

  const float* arow0;
  const float* arow1;
  const float* arow2;
  const float* arow3;
  {
    int r0 = min(m0 + 0 * 16 + lrow, M - 1);
    int r1 = min(m0 + 1 * 16 + lrow, M - 1);
    int r2 = min(m0 + 2 * 16 + lrow, M - 1);
    int r3 = min(m0 + 3 * 16 + lrow, M - 1);
    arow0 = io + (size_t)r0 * D + lkg * 8;
    arow1 = io + (size_t)r1 * D + lkg * 8;
    arow2 = io + (size_t)r2 * D + lkg * 8;
    arow3 = io + (size_t)r3 * D + lkg * 8;
  }
  const float* brow0 = W + (size_t)(n0 + 0 * 16 + lrow) * D + lkg * 8;
  const float* brow1 = W + (size_t)(n0 + 1 * 16 + lrow) * D + lkg * 8;
  const float* brow2 = W + (size_t)(n0 + 2 * 16 + lrow) * D + lkg * 8;
  const float* brow3 = W + (size_t)(n0 + 3 * 16 + lrow) * D + lkg * 8;

#pragma unroll
  for (int kk = 0; kk < 8; ++kk) {
    bf16x8 af[4], bf[4];
    af[0] = load_cvt8(arow0 + kk * 32);
    af[1] = load_cvt8(arow1 + kk * 32);
    af[2] = load_cvt8(arow2 + kk * 32);
    af[3] = load_cvt8(arow3 + kk * 32);
    bf[0] = load_cvt8(brow0 + kk * 32);
    bf[1] = load_cvt8(brow1 + kk * 32);
    bf[2] = load_cvt8(brow2 + kk * 32);
    bf[3] = load_cvt8(brow3 + kk * 32);
#pragma unroll
    for (int mb = 0; mb < 4; ++mb)
#pragma unroll
      for (int nb = 0; nb < 4; ++nb)
        acc[mb][nb] = __builtin_amdgcn_mfma_f32_16x16x32_bf16(
            af[mb], bf[nb], acc[mb][nb], 0, 0, 0);
  }

  __syncthreads();

  float bv[4];
#pragma unroll
  for (int nb = 0; nb < 4; ++nb) bv[nb] = bias[n0 + nb * 16 + lrow];

#pragma unroll
  for (int mb = 0; mb < 4; ++mb) {
#pragma unroll
    for (int reg = 0; reg < 4; ++reg) {
      int r = m0 + mb * 16 + lkg * 4 + reg;
      if (r < M) {
#pragma unroll
        for (int nb = 0; nb < 4; ++nb)
          io[(size_t)r * D + n0 + nb * 16 + lrow] = acc[mb][nb][reg] + bv[nb];
      }
    }
  }
}

extern "C" void kernel_launch(void* const* d_in, const int* in_sizes, int n_in,
                              void* d_out, int out_size, void* d_ws, size_t ws_size,
                              hipStream_t stream) {
  const float* feat = (const float*)d_in[0];
  const int* src = (const int*)d_in[1];
  const int* dst = (const int*)d_in[2];
  const float* ew = (const float*)d_in[3];
  const float* W = (const float*)d_in[4];
  const float* bias = (const float*)d_in[5];
  float* out = (float*)d_out;

  const int E = in_sizes[1];
  const int M = out_size / D;
  const long long nfeat = in_sizes[0];
  const int NC = (M + SCAN_CHUNK - 1) / SCAN_CHUNK;

  size_t off_b = ((size_t)(M + 1) * 4 + 255) & ~(size_t)255;
  size_t cur_b = ((size_t)M * 4 + 255) & ~(size_t)255;
  size_t chk_b = ((size_t)(2 * NC) * 4 + 255) & ~(size_t)255;
  size_t eid_b = ((size_t)E * 4 + 255) & ~(size_t)255;
  size_t pair_b = ((size_t)E * 8 + 255) & ~(size_t)255;
  size_t y_b = ((size_t)nfeat * 2 + 255) & ~(size_t)255;

  // Tier A: offsets | cursor | chunk | pairs | Y
  size_t need_A = off_b + cur_b + chk_b + pair_b + y_b;
  // Tier B: offsets | cursor | chunk | eid | fb
  size_t need_B = off_b + cur_b + chk_b + eid_b + y_b;
  // Tier C: offsets | cursor | chunk | eid
  size_t need_C = off_b + cur_b + chk_b + eid_b;

  const int eb = (E + 255) / 256;

  if (ws_size >= need_A && d_ws != nullptr) {
    char* ws = (char*)d_ws;
    int* offsets = (int*)ws;
    int* cursor = (int*)(ws + off_b);
    int* chunk_sum = (int*)(ws + off_b + cur_b);
    int* chunk_off = chunk_sum + NC;
    int2* pairs = (int2*)(ws + off_b + cur_b + chk_b);
    unsigned short* Y = (unsigned short*)(ws + off_b + cur_b + chk_b + pair_b);

    // Y = X @ W.T  (bf16) — independent of CSR build.
    proj_feat_mfma<<<(M + 63) / 64, 256, 0, stream>>>(feat, W, Y, M);

    hipMemsetAsync(cursor, 0, (size_t)M * 4, stream);
    hist_kernel<<<eb, 256, 0, stream>>>(dst, cursor, E);
    scan_chunk_sum<<<NC, 256, 0, stream>>>(cursor, chunk_sum, M);
    scan_chunk_off<<<1, 64, 0, stream>>>(chunk_sum, chunk_off, NC, offsets, M, E);
    scan_finalize<<<NC, 256, 0, stream>>>(cursor, offsets, chunk_off, M);
    fill_pair_kernel<<<eb, 256, 0, stream>>>(src, dst, ew, cursor, pairs, E);

    long long threads = (long long)M * 32;  // half-wave per node
    int blocks = (int)((threads + 255) / 256);
    gather_pair_kernel<<<blocks, 256, 0, stream>>>(Y, offsets, pairs, bias,
                                                   out, M);
    return;  // no post-projection needed
  }

  if (ws_size >= need_C && d_ws != nullptr) {
    char* ws = (char*)d_ws;
    int* offsets = (int*)ws;
    int* cursor = (int*)(ws + off_b);
    int* chunk_sum = (int*)(ws + off_b + cur_b);
    int* chunk_off = chunk_sum + NC;
    int* csr_eid = (int*)(ws + off_b + cur_b + chk_b);
    unsigned short* fb = (unsigned short*)(ws + off_b + cur_b + chk_b + eid_b);
    const bool use_bf16 = (ws_size >= need_B);

    if (use_bf16) {
      int cb = (int)((nfeat / 8 + 255) / 256);
      cvt_feat_kernel<<<cb, 256, 0, stream>>>(feat, fb, nfeat);
    }
    hipMemsetAsync(cursor, 0, (size_t)M * 4, stream);
    hist_kernel<<<eb, 256, 0, stream>>>(dst, cursor, E);
    scan_chunk_sum<<<NC, 256, 0, stream>>>(cursor, chunk_sum, M);
    scan_chunk_off<<<1, 64, 0, stream>>>(chunk_sum, chunk_off, NC, offsets, M, E);
    scan_finalize<<<NC, 256, 0, stream>>>(cursor, offsets, chunk_off, M);
    fill_kernel<<<eb, 256, 0, stream>>>(dst, cursor, csr_eid, E);

    long long threads = (long long)M * 64;
    int blocks = (int)((threads + 255) / 256);
    if (use_bf16) {
      gather_bf16_kernel<<<blocks, 256, 0, stream>>>(fb, offsets, csr_eid, src,
                                                     ew, out, M);
    } else {
      gather_kernel<<<blocks, 256, 0, stream>>>(feat, offsets, csr_eid, src,
                                                ew, out, M);
    }
  } else {
    hipMemsetAsync(out, 0, (size_t)out_size * sizeof(float), stream);
    long long threads = (long long)E * 64;
    int blocks = (int)((threads + 255) / 256);
    scatter_edges<<<blocks, 256, 0, stream>>>(feat, src, dst, ew, out, E);
  }

  proj_mfma<<<(M + 63) / 64, 256, 0, stream>>>(out, W, bias, M);
}